// Round 1
// baseline (802.165 us; speedup 1.0000x reference)
//
#include <hip/hip_runtime.h>
#include <cstddef>

#define D    64
#define L    128
#define G4   256   // 4*D gate rows
#define R    16    // rows per block
#define NT   256   // threads per block
#define KROWS 8192

__device__ __forceinline__ float fast_rcp(float x) {
#if defined(__has_builtin)
#if __has_builtin(__builtin_amdgcn_rcpf)
  return __builtin_amdgcn_rcpf(x);
#else
  return 1.0f / x;
#endif
#else
  return 1.0f / x;
#endif
}

__device__ __forceinline__ float sigf(float x) {
  return fast_rcp(1.0f + __expf(-x));
}
__device__ __forceinline__ float tanh_fast(float x) {
  return 2.0f * fast_rcp(1.0f + __expf(-2.0f * x)) - 1.0f;
}

// Persistent-block LSTM scan: each block owns R rows for all L steps.
// Thread j (0..255) owns gate-row j, W_hh[j][:] in registers.
__global__ __launch_bounds__(NT, 2)
void lstm_main(const float* __restrict__ x,
               const float* __restrict__ W_num,
               const float* __restrict__ b_num,
               const float* __restrict__ W_ih,
               const float* __restrict__ W_hh,
               const float* __restrict__ b_ih,
               const float* __restrict__ b_hh,
               const float* __restrict__ W_aout,
               const float* __restrict__ b_aout,
               const float* __restrict__ W_fh,
               const float* __restrict__ b_fh,
               float* __restrict__ acc_out)   // ws: [0..63]=fc_sum, [64..127]=hs_bar
{
  __shared__ float xs[R * L];     // 8 KB  x tile for this block's rows
  __shared__ float hbuf[R * D];   // 4 KB
  __shared__ float cbuf[R * D];   // 4 KB
  __shared__ float gbuf[R * G4];  // 16 KB gates, reused for h_hat in tail
  __shared__ float red[NT];       // 1 KB  tail reduction

  const int tid = threadIdx.x;
  const int k0  = blockIdx.x * R;

  // x tile: fully contiguous global -> LDS (coalesced)
  for (int idx = tid; idx < R * L; idx += NT)
    xs[idx] = x[(size_t)k0 * L + idx];
  for (int idx = tid; idx < R * D; idx += NT) { hbuf[idx] = 0.0f; cbuf[idx] = 0.0f; }

  // W_hh row j -> 64 VGPRs (256B-aligned float4 loads)
  float W[D];
  {
    const float4* wrow = (const float4*)(W_hh + (size_t)tid * D);
#pragma unroll
    for (int e4 = 0; e4 < D / 4; ++e4) {
      float4 w = wrow[e4];
      W[4*e4+0] = w.x; W[4*e4+1] = w.y; W[4*e4+2] = w.z; W[4*e4+3] = w.w;
    }
  }
  // rank-1 collapse of the input projection:
  // gate[k,t,j] = A[j]*x[k,t] + Bc[j] + sum_d h[k,d]*W_hh[j,d]
  float A = 0.0f, Bc = b_ih[tid] + b_hh[tid];
  for (int e = 0; e < D; ++e) {
    float wih = W_ih[(size_t)tid * (2 * D) + e];   // W_ih[:, :D]
    A  = fmaf(W_num[e], wih, A);
    Bc = fmaf(b_num[e], wih, Bc);
  }
  __syncthreads();

  for (int t = 0; t < L; ++t) {
    // ---- matvec: gate[r][tid] for all R rows (4 rows in flight for ILP) ----
    for (int r0 = 0; r0 < R; r0 += 4) {
      float a0 = fmaf(A, xs[(r0+0)*L + t], Bc);
      float a1 = fmaf(A, xs[(r0+1)*L + t], Bc);
      float a2 = fmaf(A, xs[(r0+2)*L + t], Bc);
      float a3 = fmaf(A, xs[(r0+3)*L + t], Bc);
      const float4* h0 = (const float4*)(hbuf + (r0+0)*D);
      const float4* h1 = (const float4*)(hbuf + (r0+1)*D);
      const float4* h2 = (const float4*)(hbuf + (r0+2)*D);
      const float4* h3 = (const float4*)(hbuf + (r0+3)*D);
#pragma unroll
      for (int e4 = 0; e4 < D/4; ++e4) {
        float4 v0 = h0[e4], v1 = h1[e4], v2 = h2[e4], v3 = h3[e4];
        a0 = fmaf(v0.x, W[4*e4+0], a0); a0 = fmaf(v0.y, W[4*e4+1], a0);
        a0 = fmaf(v0.z, W[4*e4+2], a0); a0 = fmaf(v0.w, W[4*e4+3], a0);
        a1 = fmaf(v1.x, W[4*e4+0], a1); a1 = fmaf(v1.y, W[4*e4+1], a1);
        a1 = fmaf(v1.z, W[4*e4+2], a1); a1 = fmaf(v1.w, W[4*e4+3], a1);
        a2 = fmaf(v2.x, W[4*e4+0], a2); a2 = fmaf(v2.y, W[4*e4+1], a2);
        a2 = fmaf(v2.z, W[4*e4+2], a2); a2 = fmaf(v2.w, W[4*e4+3], a2);
        a3 = fmaf(v3.x, W[4*e4+0], a3); a3 = fmaf(v3.y, W[4*e4+1], a3);
        a3 = fmaf(v3.z, W[4*e4+2], a3); a3 = fmaf(v3.w, W[4*e4+3], a3);
      }
      gbuf[(r0+0)*G4 + tid] = a0;
      gbuf[(r0+1)*G4 + tid] = a1;
      gbuf[(r0+2)*G4 + tid] = a2;
      gbuf[(r0+3)*G4 + tid] = a3;
    }
    __syncthreads();
    // ---- elementwise: 4 (r,d) pairs per thread ----
#pragma unroll
    for (int q = 0; q < (R*D)/NT; ++q) {
      int p = tid + q*NT;
      int r = p >> 6, d = p & (D-1);
      float gi = gbuf[r*G4 +           d];
      float gf = gbuf[r*G4 +     D +   d];
      float gg = gbuf[r*G4 + 2 * D +   d];
      float go = gbuf[r*G4 + 3 * D +   d];
      float c  = cbuf[p];
      float c2 = sigf(gf) * c + sigf(gi) * tanh_fast(gg);
      float h2 = sigf(go) * tanh_fast(c2);
      cbuf[p] = c2;
      hbuf[p] = h2;
    }
    __syncthreads();
  }

  // ---- fused tail: h_hat = h@W_aout.T + b; f = h_hat@W_fh.T + b;
  //      partial fc_sum = sum sig(f)*c ; partial hs_bar = sum h_hat ----
#pragma unroll
  for (int q = 0; q < (R*D)/NT; ++q) {
    int p = tid + q*NT;
    int r = p >> 6, d = p & (D-1);
    float acc = b_aout[d];
    const float* wa = W_aout + (size_t)d * D;
    const float* hr = hbuf + r * D;
#pragma unroll 8
    for (int e = 0; e < D; ++e) acc = fmaf(wa[e], hr[e], acc);
    gbuf[p] = acc;   // h_hat[r*D + d]
  }
  __syncthreads();
  float pfc = 0.0f, phs = 0.0f;
#pragma unroll
  for (int q = 0; q < (R*D)/NT; ++q) {
    int p = tid + q*NT;
    int r = p >> 6, d = p & (D-1);
    float hh = gbuf[p];
    float f  = b_fh[d];
    const float* wf  = W_fh + (size_t)d * D;
    const float* hhr = gbuf + r * D;
#pragma unroll 8
    for (int e = 0; e < D; ++e) f = fmaf(wf[e], hhr[e], f);
    pfc = fmaf(sigf(f), cbuf[p], pfc);
    phs += hh;
  }
  // block reduction over the 4 thread-groups sharing d = tid&63, then one atomic per d
  red[tid] = pfc;
  __syncthreads();
  if (tid < D)
    atomicAdd(acc_out + tid, red[tid] + red[tid+64] + red[tid+128] + red[tid+192]);
  __syncthreads();
  red[tid] = phs;
  __syncthreads();
  if (tid < D)
    atomicAdd(acc_out + D + tid, red[tid] + red[tid+64] + red[tid+128] + red[tid+192]);
}

// Tiny finish: iou = hs_bar@W_iouh.T + b; c_obj; h_obj; h_hat_obj = h_obj@W_oout.T + b
__global__ void lstm_final(const float* __restrict__ acc,   // [0..63]=fc, [64..127]=hs
                           const float* __restrict__ W_iouh,
                           const float* __restrict__ b_iouh,
                           const float* __restrict__ W_oout,
                           const float* __restrict__ b_oout,
                           float* __restrict__ out)
{
  __shared__ float hobj[D];
  __shared__ float cobj[D];
  const int d = threadIdx.x;   // 64 threads
  float vi = b_iouh[d], vo = b_iouh[D + d], vu = b_iouh[2*D + d];
  for (int e = 0; e < D; ++e) {
    float hs = acc[D + e];
    vi = fmaf(W_iouh[(size_t)d*D + e],        hs, vi);
    vo = fmaf(W_iouh[(size_t)(D + d)*D + e],  hs, vo);
    vu = fmaf(W_iouh[(size_t)(2*D + d)*D + e],hs, vu);
  }
  float c_obj = sigf(vi) * tanh_fast(vu) + acc[d];
  float h_obj = sigf(vo) * tanh_fast(c_obj);
  hobj[d] = h_obj;
  cobj[d] = c_obj;
  __syncthreads();
  float hh = b_oout[d];
  for (int e = 0; e < D; ++e) hh = fmaf(W_oout[(size_t)d*D + e], hobj[e], hh);
  out[d]     = hh;       // h_hat_obj
  out[D + d] = cobj[d];  // c_obj
}

extern "C" void kernel_launch(void* const* d_in, const int* in_sizes, int n_in,
                              void* d_out, int out_size, void* d_ws, size_t ws_size,
                              hipStream_t stream) {
  const float* x      = (const float*)d_in[0];
  const float* W_num  = (const float*)d_in[1];
  const float* b_num  = (const float*)d_in[2];
  const float* W_ih   = (const float*)d_in[3];
  const float* W_hh   = (const float*)d_in[4];
  const float* b_ih   = (const float*)d_in[5];
  const float* b_hh   = (const float*)d_in[6];
  const float* W_aout = (const float*)d_in[7];
  const float* b_aout = (const float*)d_in[8];
  const float* W_fh   = (const float*)d_in[9];
  const float* b_fh   = (const float*)d_in[10];
  const float* W_iouh = (const float*)d_in[11];
  const float* b_iouh = (const float*)d_in[12];
  const float* W_oout = (const float*)d_in[13];
  const float* b_oout = (const float*)d_in[14];
  float* acc = (float*)d_ws;
  float* out = (float*)d_out;

  // ws is re-poisoned 0xAA before every launch — zero the accumulators on stream
  hipMemsetAsync(d_ws, 0, 2 * D * sizeof(float), stream);
  lstm_main<<<KROWS / R, NT, 0, stream>>>(x, W_num, b_num, W_ih, W_hh, b_ih, b_hh,
                                          W_aout, b_aout, W_fh, b_fh, acc);
  lstm_final<<<1, D, 0, stream>>>(acc, W_iouh, b_iouh, W_oout, b_oout, out);
}

// Round 2
// 318.840 us; speedup vs baseline: 2.5159x; 2.5159x over previous
//
#include <hip/hip_runtime.h>
#include <cstddef>

#define D  64
#define L  128
#define NT 128            // 2 waves per block
#define ROWS 16           // rows per block
#define XS_STRIDE 129     // padded (conflict-free quad-strided reads)
#define GB_STRIDE 260     // padded (2-way max on gate writes/reads = free)
#define HB_STRIDE 72      // shorts; 144B row stride keeps b128 A-frag reads spread
#define KROWS 8192

typedef __attribute__((ext_vector_type(8))) short short8;
typedef __attribute__((ext_vector_type(4))) float floatx4;

__device__ __forceinline__ float fast_rcp(float x) {
#if defined(__has_builtin)
#if __has_builtin(__builtin_amdgcn_rcpf)
  return __builtin_amdgcn_rcpf(x);
#else
  return 1.0f / x;
#endif
#else
  return 1.0f / x;
#endif
}
__device__ __forceinline__ float sigf(float x) {
  return fast_rcp(1.0f + __expf(-x));
}
__device__ __forceinline__ float tanh_fast(float x) {
  return 2.0f * fast_rcp(1.0f + __expf(-2.0f * x)) - 1.0f;
}
__device__ __forceinline__ unsigned short f2bf(float f) {  // RTNE fp32->bf16 bits
  unsigned int u = __float_as_uint(f);
  u += 0x7fffu + ((u >> 16) & 1u);
  return (unsigned short)(u >> 16);
}
__device__ __forceinline__ float bf2f(unsigned short s) {
  return __uint_as_float(((unsigned int)s) << 16);
}

// Persistent 16-row LSTM scan. Wave w of the block computes gate columns
// [128w, 128w+128) via MFMA (split-bf16 hi/lo, 3 terms); elementwise phase
// splits the 16 rows 8/8 between the waves through a padded LDS gate buffer.
__global__ __launch_bounds__(NT, 1)
void lstm_main(const float* __restrict__ x,
               const float* __restrict__ W_num,
               const float* __restrict__ b_num,
               const float* __restrict__ W_ih,
               const float* __restrict__ W_hh,
               const float* __restrict__ b_ih,
               const float* __restrict__ b_hh,
               const float* __restrict__ W_aout,
               const float* __restrict__ b_aout,
               const float* __restrict__ W_fh,
               const float* __restrict__ b_fh,
               float* __restrict__ acc_out)   // [0..63]=fc_sum, [64..127]=hs_bar
{
  __shared__ __align__(16) float xs[ROWS * XS_STRIDE];     // 8.1 KB
  __shared__ __align__(16) float gbuf[ROWS * GB_STRIDE];   // 16.3 KB
  __shared__ __align__(16) short hb_hi[ROWS * HB_STRIDE];  // 2.25 KB
  __shared__ __align__(16) short hb_lo[ROWS * HB_STRIDE];  // 2.25 KB

  const int tid  = threadIdx.x;
  const int w    = tid >> 6;
  const int lane = tid & 63;
  const int quad = lane >> 4;
  const int c16  = lane & 15;
  const int k0   = blockIdx.x * ROWS;

  // ---- stage x tile (16 rows x 128 t), padded row stride ----
  for (int i = tid; i < ROWS * (L / 4); i += NT) {
    int r = i >> 5, c4 = i & 31;
    float4 v = ((const float4*)(x + (size_t)(k0 + r) * L))[c4];
    float* dst = &xs[r * XS_STRIDE + c4 * 4];
    dst[0] = v.x; dst[1] = v.y; dst[2] = v.z; dst[3] = v.w;
  }
  for (int i = tid; i < ROWS * HB_STRIDE; i += NT) { hb_hi[i] = 0; hb_lo[i] = 0; }

  // ---- rank-1 x-projection per gate column: gate += A[j]*x + Bc[j] ----
  float An[8], Bcn[8];
#pragma unroll
  for (int n = 0; n < 8; ++n) {
    int j = w * 128 + n * 16 + c16;
    float a = 0.0f, b = b_ih[j] + b_hh[j];
    for (int e = 0; e < D; ++e) {
      float wih = W_ih[(size_t)j * (2 * D) + e];   // W_ih[:, :D]
      a = fmaf(W_num[e], wih, a);
      b = fmaf(b_num[e], wih, b);
    }
    An[n] = a; Bcn[n] = b;
  }

  // ---- W_hh B-fragments (constant across steps), hi/lo bf16 split ----
  // B[k][n] layout: n = lane&15, k = quad*8 + j
  short8 Bhi[2][8], Blo[2][8];
#pragma unroll
  for (int k = 0; k < 2; ++k) {
#pragma unroll
    for (int n = 0; n < 8; ++n) {
      const float* wp = W_hh + (size_t)(w * 128 + n * 16 + c16) * D + k * 32 + quad * 8;
      short8 hi8, lo8;
#pragma unroll
      for (int j = 0; j < 8; ++j) {
        float v = wp[j];
        unsigned short h = f2bf(v);
        hi8[j] = (short)h;
        lo8[j] = (short)f2bf(v - bf2f(h));
      }
      Bhi[k][n] = hi8; Blo[k][n] = lo8;
    }
  }

  float creg[8];
#pragma unroll
  for (int r = 0; r < 8; ++r) creg[r] = 0.0f;

  __syncthreads();

  for (int t = 0; t < L; ++t) {
    // A-fragments of h (previous step): m = c16, k = 32k + quad*8 + j
    short8 ahi[2], alo[2];
#pragma unroll
    for (int k = 0; k < 2; ++k) {
      int off = c16 * HB_STRIDE + k * 32 + quad * 8;
      ahi[k] = *(const short8*)&hb_hi[off];
      alo[k] = *(const short8*)&hb_lo[off];
    }
    floatx4 acc[8];
#pragma unroll
    for (int n = 0; n < 8; ++n) acc[n] = (floatx4){0.f, 0.f, 0.f, 0.f};
#pragma unroll
    for (int k = 0; k < 2; ++k) {
#pragma unroll
      for (int n = 0; n < 8; ++n) {
        acc[n] = __builtin_amdgcn_mfma_f32_16x16x32_bf16(ahi[k], Bhi[k][n], acc[n], 0, 0, 0);
        acc[n] = __builtin_amdgcn_mfma_f32_16x16x32_bf16(alo[k], Bhi[k][n], acc[n], 0, 0, 0);
        acc[n] = __builtin_amdgcn_mfma_f32_16x16x32_bf16(ahi[k], Blo[k][n], acc[n], 0, 0, 0);
      }
    }
    // x-term + bias in fp32, scatter gates to LDS (C layout: row=quad*4+r, col=16n+c16)
    float xv[4];
#pragma unroll
    for (int r = 0; r < 4; ++r) xv[r] = xs[(quad * 4 + r) * XS_STRIDE + t];
#pragma unroll
    for (int n = 0; n < 8; ++n) {
#pragma unroll
      for (int r = 0; r < 4; ++r) {
        gbuf[(quad * 4 + r) * GB_STRIDE + w * 128 + n * 16 + c16] =
            acc[n][r] + fmaf(An[n], xv[r], Bcn[n]);
      }
    }
    __syncthreads();

    // elementwise: lane = d, wave w handles rows 8w..8w+7
#pragma unroll
    for (int r = 0; r < 8; ++r) {
      int row = w * 8 + r;
      const float* g = &gbuf[row * GB_STRIDE];
      float gi = g[lane], gf = g[64 + lane], gg = g[128 + lane], go = g[192 + lane];
      float c2 = sigf(gf) * creg[r] + sigf(gi) * tanh_fast(gg);
      float h2 = sigf(go) * tanh_fast(c2);
      creg[r] = c2;
      unsigned short h = f2bf(h2);
      hb_hi[row * HB_STRIDE + lane] = (short)h;
      hb_lo[row * HB_STRIDE + lane] = (short)f2bf(h2 - bf2f(h));
    }
    __syncthreads();
  }

  // ---- tail: h_hat = h@W_aout.T+b ; f = h_hat@W_fh.T+b ; partial sums ----
  // reconstruct h fp32 into gbuf[row][0..63] (i-gate cols are dead now)
#pragma unroll
  for (int r = 0; r < 8; ++r) {
    int row = w * 8 + r;
    gbuf[row * GB_STRIDE + lane] =
        bf2f((unsigned short)hb_hi[row * HB_STRIDE + lane]) +
        bf2f((unsigned short)hb_lo[row * HB_STRIDE + lane]);
  }
  __syncthreads();

  float hhat[8];
#pragma unroll
  for (int r = 0; r < 8; ++r) hhat[r] = b_aout[lane];
  for (int e4 = 0; e4 < 16; ++e4) {
    float4 wv = ((const float4*)(W_aout + (size_t)lane * D))[e4];
#pragma unroll
    for (int r = 0; r < 8; ++r) {
      const float* hp = &gbuf[(w * 8 + r) * GB_STRIDE + e4 * 4];
      hhat[r] = fmaf(wv.x, hp[0], hhat[r]);
      hhat[r] = fmaf(wv.y, hp[1], hhat[r]);
      hhat[r] = fmaf(wv.z, hp[2], hhat[r]);
      hhat[r] = fmaf(wv.w, hp[3], hhat[r]);
    }
  }
  __syncthreads();
#pragma unroll
  for (int r = 0; r < 8; ++r)
    gbuf[(w * 8 + r) * GB_STRIDE + 64 + lane] = hhat[r];   // exchange h_hat
  __syncthreads();

  float pfc = 0.0f, phs = 0.0f;
#pragma unroll
  for (int r = 0; r < 8; ++r) phs += hhat[r];
  {
    float facc[8];
#pragma unroll
    for (int r = 0; r < 8; ++r) facc[r] = b_fh[lane];
    for (int e4 = 0; e4 < 16; ++e4) {
      float4 wv = ((const float4*)(W_fh + (size_t)lane * D))[e4];
#pragma unroll
      for (int r = 0; r < 8; ++r) {
        const float* hp = &gbuf[(w * 8 + r) * GB_STRIDE + 64 + e4 * 4];
        facc[r] = fmaf(wv.x, hp[0], facc[r]);
        facc[r] = fmaf(wv.y, hp[1], facc[r]);
        facc[r] = fmaf(wv.z, hp[2], facc[r]);
        facc[r] = fmaf(wv.w, hp[3], facc[r]);
      }
    }
#pragma unroll
    for (int r = 0; r < 8; ++r) pfc = fmaf(sigf(facc[r]), creg[r], pfc);
  }

  // block reduction (2 waves share lane=d) -> one atomic per d
  float* red = xs;
  red[tid] = pfc;
  __syncthreads();
  if (tid < D) atomicAdd(acc_out + tid, red[tid] + red[tid + 64]);
  __syncthreads();
  red[tid] = phs;
  __syncthreads();
  if (tid < D) atomicAdd(acc_out + D + tid, red[tid] + red[tid + 64]);
}

// Tiny finish: iou = hs_bar@W_iouh.T + b; c_obj; h_obj; h_hat_obj = h_obj@W_oout.T + b
__global__ void lstm_final(const float* __restrict__ acc,   // [0..63]=fc, [64..127]=hs
                           const float* __restrict__ W_iouh,
                           const float* __restrict__ b_iouh,
                           const float* __restrict__ W_oout,
                           const float* __restrict__ b_oout,
                           float* __restrict__ out)
{
  __shared__ float hobj[D];
  __shared__ float cobj[D];
  const int d = threadIdx.x;   // 64 threads
  float vi = b_iouh[d], vo = b_iouh[D + d], vu = b_iouh[2 * D + d];
  for (int e = 0; e < D; ++e) {
    float hs = acc[D + e];
    vi = fmaf(W_iouh[(size_t)d * D + e],           hs, vi);
    vo = fmaf(W_iouh[(size_t)(D + d) * D + e],     hs, vo);
    vu = fmaf(W_iouh[(size_t)(2 * D + d) * D + e], hs, vu);
  }
  float c_obj = sigf(vi) * tanh_fast(vu) + acc[d];
  float h_obj = sigf(vo) * tanh_fast(c_obj);
  hobj[d] = h_obj;
  cobj[d] = c_obj;
  __syncthreads();
  float hh = b_oout[d];
  for (int e = 0; e < D; ++e) hh = fmaf(W_oout[(size_t)d * D + e], hobj[e], hh);
  out[d]     = hh;       // h_hat_obj
  out[D + d] = cobj[d];  // c_obj
}

extern "C" void kernel_launch(void* const* d_in, const int* in_sizes, int n_in,
                              void* d_out, int out_size, void* d_ws, size_t ws_size,
                              hipStream_t stream) {
  const float* x      = (const float*)d_in[0];
  const float* W_num  = (const float*)d_in[1];
  const float* b_num  = (const float*)d_in[2];
  const float* W_ih   = (const float*)d_in[3];
  const float* W_hh   = (const float*)d_in[4];
  const float* b_ih   = (const float*)d_in[5];
  const float* b_hh   = (const float*)d_in[6];
  const float* W_aout = (const float*)d_in[7];
  const float* b_aout = (const float*)d_in[8];
  const float* W_fh   = (const float*)d_in[9];
  const float* b_fh   = (const float*)d_in[10];
  const float* W_iouh = (const float*)d_in[11];
  const float* b_iouh = (const float*)d_in[12];
  const float* W_oout = (const float*)d_in[13];
  const float* b_oout = (const float*)d_in[14];
  float* acc = (float*)d_ws;
  float* out = (float*)d_out;

  hipMemsetAsync(d_ws, 0, 2 * D * sizeof(float), stream);
  lstm_main<<<KROWS / ROWS, NT, 0, stream>>>(x, W_num, b_num, W_ih, W_hh, b_ih, b_hh,
                                             W_aout, b_aout, W_fh, b_fh, acc);
  lstm_final<<<1, D, 0, stream>>>(acc, W_iouh, b_iouh, W_oout, b_oout, out);
}

// Round 3
// 241.646 us; speedup vs baseline: 3.3196x; 1.3195x over previous
//
#include <hip/hip_runtime.h>
#include <cstddef>

#define D  64
#define L  128
#define NT 256            // 4 waves per block
#define ROWS 16           // rows per block (one M=16 MFMA tile)
#define XS_STRIDE 129     // padded floats
#define HBS 72            // shorts; uniform 8-lane start-bank spread for b128 reads
#define KROWS 8192

typedef __attribute__((ext_vector_type(8))) short short8;
typedef __attribute__((ext_vector_type(4))) float floatx4;

__device__ __forceinline__ float fast_rcp(float x) {
#if defined(__has_builtin)
#if __has_builtin(__builtin_amdgcn_rcpf)
  return __builtin_amdgcn_rcpf(x);
#else
  return 1.0f / x;
#endif
#else
  return 1.0f / x;
#endif
}
__device__ __forceinline__ float sigf(float x) {
  return fast_rcp(1.0f + __expf(-x));
}
__device__ __forceinline__ float tanh_fast(float x) {
  return 2.0f * fast_rcp(1.0f + __expf(-2.0f * x)) - 1.0f;
}
__device__ __forceinline__ unsigned short f2bf_rtne(float f) {
  unsigned int u = __float_as_uint(f);
  u += 0x7fffu + ((u >> 16) & 1u);
  return (unsigned short)(u >> 16);
}
__device__ __forceinline__ float bf2f(unsigned short s) {
  return __uint_as_float(((unsigned int)s) << 16);
}

// Persistent 16-row LSTM scan, register-resident gates.
// Wave w owns d in [16w,16w+16) for ALL FOUR gates: its 4 accumulators are
// exactly the (i,f,g,o) values of its own cells -> elementwise in registers,
// no gate LDS buffer, ONE barrier/step (double-buffered h hi/lo exchange).
__global__ __launch_bounds__(NT, 2)
void lstm_main(const float* __restrict__ x,
               const float* __restrict__ W_num,
               const float* __restrict__ b_num,
               const float* __restrict__ W_ih,
               const float* __restrict__ W_hh,
               const float* __restrict__ b_ih,
               const float* __restrict__ b_hh,
               const float* __restrict__ W_aout,
               const float* __restrict__ b_aout,
               const float* __restrict__ W_fh,
               const float* __restrict__ b_fh,
               float* __restrict__ acc_out)   // [0..63]=fc_sum, [64..127]=hs_bar
{
  __shared__ __align__(16) float xs[ROWS * XS_STRIDE];       // 8.2 KB (x, later h/h_hat)
  __shared__ __align__(16) short hb_hi[2][ROWS * HBS];       // 4.5 KB (double-buffered)
  __shared__ __align__(16) short hb_lo[2][ROWS * HBS];       // 4.5 KB

  const int tid  = threadIdx.x;
  const int w    = tid >> 6;       // wave 0..3
  const int lane = tid & 63;
  const int quad = lane >> 4;
  const int c16  = lane & 15;
  const int k0   = blockIdx.x * ROWS;
  const int dcol = w * 16 + c16;   // this lane's hidden index d

  // ---- stage x tile (16 rows x 128), contiguous & coalesced ----
  for (int i = tid; i < ROWS * (L / 4); i += NT) {
    int r = i >> 5, c4 = i & 31;
    float4 v = ((const float4*)(x + (size_t)(k0 + r) * L))[c4];
    float* dst = &xs[r * XS_STRIDE + c4 * 4];
    dst[0] = v.x; dst[1] = v.y; dst[2] = v.z; dst[3] = v.w;
  }
  for (int i = tid; i < ROWS * HBS; i += NT) { hb_hi[0][i] = 0; hb_lo[0][i] = 0; }

  // ---- rank-1 x-projection constants per gate: j = g*64 + dcol ----
  float An[4], Bc[4];
#pragma unroll
  for (int g = 0; g < 4; ++g) {
    int j = g * 64 + dcol;
    float a = 0.0f, b = b_ih[j] + b_hh[j];
    for (int e = 0; e < D; ++e) {
      float wih = W_ih[(size_t)j * (2 * D) + e];   // W_ih[:, :D]
      a = fmaf(W_num[e], wih, a);
      b = fmaf(b_num[e], wih, b);
    }
    An[g] = a; Bc[g] = b;
  }

  // ---- W_hh B-fragments (constant): B[k=kk*32+quad*8+j][n=c16] = W_hh[col][k] ----
  short8 Bhi[4][2], Blo[4][2];
#pragma unroll
  for (int g = 0; g < 4; ++g) {
#pragma unroll
    for (int kk = 0; kk < 2; ++kk) {
      const float* wp = W_hh + (size_t)(g * 64 + dcol) * D + kk * 32 + quad * 8;
      short8 hi8, lo8;
#pragma unroll
      for (int j = 0; j < 8; ++j) {
        float v = wp[j];
        unsigned short h = f2bf_rtne(v);
        hi8[j] = (short)h;
        lo8[j] = (short)f2bf_rtne(v - bf2f(h));
      }
      Bhi[g][kk] = hi8; Blo[g][kk] = lo8;
    }
  }

  float creg[4] = {0.f, 0.f, 0.f, 0.f};
  float hreg[4] = {0.f, 0.f, 0.f, 0.f};
  __syncthreads();

  int p = 0;
  for (int t = 0; t < L; ++t) {
    // A-fragments of h(t-1): m=c16, k=kk*32+quad*8+j  (same for all 4 waves)
    short8 ahi[2], alo[2];
#pragma unroll
    for (int kk = 0; kk < 2; ++kk) {
      int off = c16 * HBS + kk * 32 + quad * 8;
      ahi[kk] = *(const short8*)&hb_hi[p][off];
      alo[kk] = *(const short8*)&hb_lo[p][off];
    }
    // x-term + bias folded into C-operand init
    float xv[4];
#pragma unroll
    for (int r = 0; r < 4; ++r) xv[r] = xs[(quad * 4 + r) * XS_STRIDE + t];
    floatx4 acc[4];
#pragma unroll
    for (int g = 0; g < 4; ++g)
      acc[g] = (floatx4){fmaf(An[g], xv[0], Bc[g]), fmaf(An[g], xv[1], Bc[g]),
                         fmaf(An[g], xv[2], Bc[g]), fmaf(An[g], xv[3], Bc[g])};
#pragma unroll
    for (int kk = 0; kk < 2; ++kk) {
#pragma unroll
      for (int g = 0; g < 4; ++g) {
        acc[g] = __builtin_amdgcn_mfma_f32_16x16x32_bf16(ahi[kk], Bhi[g][kk], acc[g], 0, 0, 0);
        acc[g] = __builtin_amdgcn_mfma_f32_16x16x32_bf16(alo[kk], Bhi[g][kk], acc[g], 0, 0, 0);
        acc[g] = __builtin_amdgcn_mfma_f32_16x16x32_bf16(ahi[kk], Blo[g][kk], acc[g], 0, 0, 0);
      }
    }
    // elementwise fully in registers: lane's cells are (row=quad*4+r, d=dcol)
#pragma unroll
    for (int r = 0; r < 4; ++r) {
      float gi = acc[0][r], gf = acc[1][r], gg = acc[2][r], go = acc[3][r];
      float c2 = sigf(gf) * creg[r] + sigf(gi) * tanh_fast(gg);
      float h2 = sigf(go) * tanh_fast(c2);
      creg[r] = c2;
      hreg[r] = h2;
      // truncating hi/lo split (lo captures the residual exactly)
      unsigned int u = __float_as_uint(h2);
      unsigned short hi = (unsigned short)(u >> 16);
      float hif = __uint_as_float(u & 0xffff0000u);
      unsigned short lo = (unsigned short)(__float_as_uint(h2 - hif) >> 16);
      int row = quad * 4 + r;
      hb_hi[p ^ 1][row * HBS + dcol] = (short)hi;
      hb_lo[p ^ 1][row * HBS + dcol] = (short)lo;
    }
    __syncthreads();
    p ^= 1;
  }

  // ---- tail: h_hat = h@W_aout.T+b ; f = h_hat@W_fh.T+b ; partial sums ----
  // x tile is dead: reuse xs. h fp32 -> xs[row][0..63], h_hat -> xs[row][64..127]
#pragma unroll
  for (int r = 0; r < 4; ++r) xs[(quad * 4 + r) * XS_STRIDE + dcol] = hreg[r];
  __syncthreads();

  float hhat[4];
#pragma unroll
  for (int r = 0; r < 4; ++r) {
    float a = b_aout[dcol];
    const float4* wa = (const float4*)(W_aout + (size_t)dcol * D);
    const float* hp = &xs[(quad * 4 + r) * XS_STRIDE];
#pragma unroll
    for (int e4 = 0; e4 < 16; ++e4) {
      float4 wv = wa[e4];
      a = fmaf(wv.x, hp[e4 * 4 + 0], a);
      a = fmaf(wv.y, hp[e4 * 4 + 1], a);
      a = fmaf(wv.z, hp[e4 * 4 + 2], a);
      a = fmaf(wv.w, hp[e4 * 4 + 3], a);
    }
    hhat[r] = a;
  }
  __syncthreads();
#pragma unroll
  for (int r = 0; r < 4; ++r) xs[(quad * 4 + r) * XS_STRIDE + 64 + dcol] = hhat[r];
  __syncthreads();

  float pfc = 0.0f, phs = 0.0f;
#pragma unroll
  for (int r = 0; r < 4; ++r) {
    float f = b_fh[dcol];
    const float4* wf = (const float4*)(W_fh + (size_t)dcol * D);
    const float* hp = &xs[(quad * 4 + r) * XS_STRIDE + 64];
#pragma unroll
    for (int e4 = 0; e4 < 16; ++e4) {
      float4 wv = wf[e4];
      f = fmaf(wv.x, hp[e4 * 4 + 0], f);
      f = fmaf(wv.y, hp[e4 * 4 + 1], f);
      f = fmaf(wv.z, hp[e4 * 4 + 2], f);
      f = fmaf(wv.w, hp[e4 * 4 + 3], f);
    }
    pfc = fmaf(sigf(f), creg[r], pfc);
    phs += hhat[r];
  }
  // reduce over quads (lanes c16, c16+16, c16+32, c16+48), one atomic per d
  pfc += __shfl_xor(pfc, 16); pfc += __shfl_xor(pfc, 32);
  phs += __shfl_xor(phs, 16); phs += __shfl_xor(phs, 32);
  if (quad == 0) {
    atomicAdd(acc_out + dcol, pfc);
    atomicAdd(acc_out + D + dcol, phs);
  }
}

// Tiny finish: iou = hs_bar@W_iouh.T + b; c_obj; h_obj; h_hat_obj = h_obj@W_oout.T + b
__global__ void lstm_final(const float* __restrict__ acc,   // [0..63]=fc, [64..127]=hs
                           const float* __restrict__ W_iouh,
                           const float* __restrict__ b_iouh,
                           const float* __restrict__ W_oout,
                           const float* __restrict__ b_oout,
                           float* __restrict__ out)
{
  __shared__ float hobj[D];
  __shared__ float cobj[D];
  const int d = threadIdx.x;   // 64 threads
  float vi = b_iouh[d], vo = b_iouh[D + d], vu = b_iouh[2 * D + d];
  for (int e = 0; e < D; ++e) {
    float hs = acc[D + e];
    vi = fmaf(W_iouh[(size_t)d * D + e],           hs, vi);
    vo = fmaf(W_iouh[(size_t)(D + d) * D + e],     hs, vo);
    vu = fmaf(W_iouh[(size_t)(2 * D + d) * D + e], hs, vu);
  }
  float c_obj = sigf(vi) * tanh_fast(vu) + acc[d];
  float h_obj = sigf(vo) * tanh_fast(c_obj);
  hobj[d] = h_obj;
  cobj[d] = c_obj;
  __syncthreads();
  float hh = b_oout[d];
  for (int e = 0; e < D; ++e) hh = fmaf(W_oout[(size_t)d * D + e], hobj[e], hh);
  out[d]     = hh;       // h_hat_obj
  out[D + d] = cobj[d];  // c_obj
}

extern "C" void kernel_launch(void* const* d_in, const int* in_sizes, int n_in,
                              void* d_out, int out_size, void* d_ws, size_t ws_size,
                              hipStream_t stream) {
  const float* x      = (const float*)d_in[0];
  const float* W_num  = (const float*)d_in[1];
  const float* b_num  = (const float*)d_in[2];
  const float* W_ih   = (const float*)d_in[3];
  const float* W_hh   = (const float*)d_in[4];
  const float* b_ih   = (const float*)d_in[5];
  const float* b_hh   = (const float*)d_in[6];
  const float* W_aout = (const float*)d_in[7];
  const float* b_aout = (const float*)d_in[8];
  const float* W_fh   = (const float*)d_in[9];
  const float* b_fh   = (const float*)d_in[10];
  const float* W_iouh = (const float*)d_in[11];
  const float* b_iouh = (const float*)d_in[12];
  const float* W_oout = (const float*)d_in[13];
  const float* b_oout = (const float*)d_in[14];
  float* acc = (float*)d_ws;
  float* out = (float*)d_out;

  hipMemsetAsync(d_ws, 0, 2 * D * sizeof(float), stream);
  lstm_main<<<KROWS / ROWS, NT, 0, stream>>>(x, W_num, b_num, W_ih, W_hh, b_ih, b_hh,
                                             W_aout, b_aout, W_fh, b_fh, acc);
  lstm_final<<<1, D, 0, stream>>>(acc, W_iouh, b_iouh, W_oout, b_oout, out);
}